// Round 10
// baseline (165.625 us; speedup 1.0000x reference)
//
#include <hip/hip_runtime.h>
#include <hip/hip_bf16.h>
#include <stdint.h>

typedef __bf16 bf16_t;
typedef __bf16 bf16x4 __attribute__((ext_vector_type(4)));
typedef __bf16 bf16x8 __attribute__((ext_vector_type(8)));
typedef float  f32x4  __attribute__((ext_vector_type(4)));
typedef unsigned u32x2 __attribute__((ext_vector_type(2)));

#define MFMA16(a,b,c) __builtin_amdgcn_mfma_f32_16x16x32_bf16((a),(b),(c),0,0,0)

static constexpr int DIM = 1024, HEADS = 16, HD = 64, NB = 2, NQ = 2048, NKK = 2048;
static constexpr int MROWS = NB * NQ; // 4096 token rows
static constexpr float SCALE_Q = 0.18033688011112042f; // 0.125 * log2(e)

// ---------------- fused f32 -> bf16 convert (all 7 tensors, 1 launch) -------
__global__ void cvt_all(const float* __restrict__ q, const float* __restrict__ k,
                        const float* __restrict__ v, const float* __restrict__ wq,
                        const float* __restrict__ wk, const float* __restrict__ wv,
                        const float* __restrict__ wo,
                        bf16_t* qb, bf16_t* kb, bf16_t* vb,
                        bf16_t* wqb, bf16_t* wkb, bf16_t* wvb, bf16_t* wob) {
  const int seg = blockIdx.y;
  const float* src; bf16_t* dst;
  size_t base;
  if (seg < 12) {
    int t = seg >> 2;                       // 0=q 1=k 2=v
    src = t == 0 ? q : t == 1 ? k : v;
    dst = t == 0 ? qb : t == 1 ? kb : vb;
    base = (size_t)(seg & 3) * 262144;      // quarter of 1M float4
  } else {
    int t = seg - 12;
    src = t == 0 ? wq : t == 1 ? wk : t == 2 ? wv : wo;
    dst = t == 0 ? wqb : t == 1 ? wkb : t == 2 ? wvb : wob;
    base = 0;
  }
  size_t i = base + blockIdx.x * 256 + threadIdx.x;
  float4 val = reinterpret_cast<const float4*>(src)[i];
  bf16x4 o;
  o[0] = (bf16_t)val.x; o[1] = (bf16_t)val.y; o[2] = (bf16_t)val.z; o[3] = (bf16_t)val.w;
  *reinterpret_cast<bf16x4*>(dst + i * 4) = o;
}

// ---------------- LDS staging with chunk-XOR swizzle ----------------
template<int ROWS>
__device__ __forceinline__ void stage_swz(const bf16_t* gbase, int gstride, bf16_t* lds, int tid) {
#pragma unroll
  for (int c = 0; c < ROWS / 32; ++c) {
    int p = c * 256 + tid;                        // 16B-chunk index
    int r = p >> 3, x = p & 7;
    const bf16_t* src = gbase + (size_t)r * gstride + ((x ^ (r & 7)) << 3);
    __builtin_amdgcn_global_load_lds(
        (const __attribute__((address_space(1))) void*)src,
        (__attribute__((address_space(3))) void*)(lds + (p << 3)),
        16, 0, 0);
  }
}

__device__ __forceinline__ bf16x8 lds_read8_swz(const bf16_t* lds, int row, int chunk) {
  int sc = chunk ^ (row & 7);
  return *reinterpret_cast<const bf16x8*>(lds + row * 64 + (sc << 3));
}

__device__ __forceinline__ unsigned cvtpk_bf16(float lo, float hi) {
  unsigned r;
  asm("v_cvt_pk_bf16_f32 %0, %1, %2" : "=v"(r) : "v"(lo), "v"(hi));
  return r;
}

// ---------------- fused QKV projection GEMM --------------------------------
// CROSS-attention: each projection has its OWN token input.
__global__ __launch_bounds__(256) void gemm_qkv(const bf16_t* __restrict__ qb,
                                                const bf16_t* __restrict__ kb,
                                                const bf16_t* __restrict__ vb,
                                                const bf16_t* __restrict__ Wq,
                                                const bf16_t* __restrict__ Wk,
                                                const bf16_t* __restrict__ Wv,
                                                bf16_t* __restrict__ Qp,
                                                bf16_t* __restrict__ Kp,
                                                bf16_t* __restrict__ Vt) {
  constexpr int K = DIM, N = DIM;
  __shared__ __align__(16) bf16_t As[128 * 64];
  __shared__ __align__(16) bf16_t Bs[128 * 64];
  const int tid = threadIdx.x;
  const int lane = tid & 63, wid = tid >> 6;
  const int l15 = lane & 15, lg = lane >> 4;
  const int wr = wid >> 1, wc = wid & 1;
  const int bn = blockIdx.x, bm = blockIdx.y;
  const int sel = bn >> 3, bnl = bn & 7;

  const bf16_t* A  = sel == 0 ? qb : sel == 1 ? kb : vb;
  const bf16_t* Bt = sel == 0 ? Wq : sel == 1 ? Wk : Wv;
  const bf16_t* Abase = A + (size_t)(bm * 128) * K;
  const bf16_t* Bbase = Bt + (size_t)(bnl * 128) * K;

  f32x4 acc[4][4];
#pragma unroll
  for (int m = 0; m < 4; ++m)
#pragma unroll
    for (int n = 0; n < 4; ++n) acc[m][n] = (f32x4){0.f, 0.f, 0.f, 0.f};

  for (int k0 = 0; k0 < K; k0 += 64) {
    __syncthreads();
    stage_swz<128>(Abase + k0, K, As, tid);
    stage_swz<128>(Bbase + k0, K, Bs, tid);
    __syncthreads();
#pragma unroll
    for (int kk = 0; kk < 2; ++kk) {
      bf16x8 af[4], bfr[4];
#pragma unroll
      for (int m = 0; m < 4; ++m) af[m] = lds_read8_swz(As, wr * 64 + m * 16 + l15, kk * 4 + lg);
#pragma unroll
      for (int n = 0; n < 4; ++n) bfr[n] = lds_read8_swz(Bs, wc * 64 + n * 16 + l15, kk * 4 + lg);
#pragma unroll
      for (int m = 0; m < 4; ++m)
#pragma unroll
        for (int n = 0; n < 4; ++n)
          acc[m][n] = MFMA16(af[m], bfr[n], acc[m][n]);
    }
  }

  if (sel == 2) {
#pragma unroll
    for (int m = 0; m < 4; ++m) {
      int row0 = bm * 128 + wr * 64 + m * 16 + lg * 4;
      int bb = row0 >> 11, kv = row0 & 2047;
#pragma unroll
      for (int n = 0; n < 4; ++n) {
        int col = bnl * 128 + wc * 64 + n * 16 + l15;
        int hh = col >> 6, dd = col & 63;
        bf16x4 pk;
#pragma unroll
        for (int j = 0; j < 4; ++j) pk[j] = (bf16_t)acc[m][n][j];
        *reinterpret_cast<bf16x4*>(Vt + (((size_t)((bb * 16 + hh) * 64 + dd)) << 11) + kv) = pk;
      }
    }
  } else {
    bf16_t* Cout = sel == 0 ? Qp : Kp;
    const float scale = sel == 0 ? SCALE_Q : 1.0f;
#pragma unroll
    for (int m = 0; m < 4; ++m)
#pragma unroll
      for (int n = 0; n < 4; ++n)
#pragma unroll
        for (int j = 0; j < 4; ++j) {
          int row = bm * 128 + wr * 64 + m * 16 + lg * 4 + j;
          int col = bnl * 128 + wc * 64 + n * 16 + l15;
          Cout[(size_t)row * N + col] = (bf16_t)(acc[m][n][j] * scale);
        }
  }
}

// ---------------- output projection GEMM (f32 + bias) ----------------------
__global__ __launch_bounds__(256) void gemm_out(const bf16_t* __restrict__ A,
                                                const bf16_t* __restrict__ Bt,
                                                float* __restrict__ Cout,
                                                const float* __restrict__ bias) {
  constexpr int K = DIM, N = DIM;
  __shared__ __align__(16) bf16_t As[128 * 64];
  __shared__ __align__(16) bf16_t Bs[128 * 64];
  const int tid = threadIdx.x;
  const int lane = tid & 63, wid = tid >> 6;
  const int l15 = lane & 15, lg = lane >> 4;
  const int wr = wid >> 1, wc = wid & 1;
  const int bn = blockIdx.x, bm = blockIdx.y;

  const bf16_t* Abase = A + (size_t)(bm * 128) * K;
  const bf16_t* Bbase = Bt + (size_t)(bn * 128) * K;

  f32x4 acc[4][4];
#pragma unroll
  for (int m = 0; m < 4; ++m)
#pragma unroll
    for (int n = 0; n < 4; ++n) acc[m][n] = (f32x4){0.f, 0.f, 0.f, 0.f};

  for (int k0 = 0; k0 < K; k0 += 64) {
    __syncthreads();
    stage_swz<128>(Abase + k0, K, As, tid);
    stage_swz<128>(Bbase + k0, K, Bs, tid);
    __syncthreads();
#pragma unroll
    for (int kk = 0; kk < 2; ++kk) {
      bf16x8 af[4], bfr[4];
#pragma unroll
      for (int m = 0; m < 4; ++m) af[m] = lds_read8_swz(As, wr * 64 + m * 16 + l15, kk * 4 + lg);
#pragma unroll
      for (int n = 0; n < 4; ++n) bfr[n] = lds_read8_swz(Bs, wc * 64 + n * 16 + l15, kk * 4 + lg);
#pragma unroll
      for (int m = 0; m < 4; ++m)
#pragma unroll
        for (int n = 0; n < 4; ++n)
          acc[m][n] = MFMA16(af[m], bfr[n], acc[m][n]);
    }
  }

#pragma unroll
  for (int m = 0; m < 4; ++m)
#pragma unroll
    for (int n = 0; n < 4; ++n)
#pragma unroll
      for (int j = 0; j < 4; ++j) {
        int row = bm * 128 + wr * 64 + m * 16 + lg * 4 + j;
        int col = bn * 128 + wc * 64 + n * 16 + l15;
        Cout[(size_t)row * N + col] = acc[m][n][j] + bias[col];
      }
}

// ---------------- fused flash attention (R9 + counted-vmcnt barriers, T3/T4)-
// grid (NQ/64, HEADS, B) XCD-swizzled; 4 waves x 16 q (q = wid*16 + l15).
// Steady-state iter t:
//   A: s_barrier            -- prev-iter LDS reads retired (MFMA issue forces
//                              lgkm drain before barrier in program order)
//   B: stage V(t+1)->Vs[(t+1)&1], K(t+2)->Ks[t&1]   (4 loads, stay in flight)
//   C: s_waitcnt vmcnt(4)   -- waits ONLY for iter t-1's 4 loads (never 0)
//   D: s_barrier            -- all waves' t-1 stages visible
//   E: QK(t+1)  F: softmax(t)+P  G: PV(t)
// Write-after-read pairs separated by A; read-after-stage by C/D.
// Tail peels vmcnt 4 -> 2 -> 0. LDS = 40960B -> 4 blocks/CU.
__global__ __launch_bounds__(256) void attn_fused(const bf16_t* __restrict__ Qp,
                                                  const bf16_t* __restrict__ Kp,
                                                  const bf16_t* __restrict__ Vt,
                                                  bf16_t* __restrict__ Xa) {
  __shared__ __align__(16) bf16_t Ks[2][64 * 64];
  __shared__ __align__(16) bf16_t Vs[2][64 * 64];
  __shared__ __align__(16) bf16_t Ps[4][16 * 64];   // per-wave, pad-free, row-rotated
  const int tid = threadIdx.x;
  const int lane = tid & 63, wid = tid >> 6;
  const int l15 = lane & 15, lg = lane >> 4;
  const int rot = (l15 & 7) * 8;

  // bijective XCD swizzle over 1024 workgroups: XCD k hosts 4 heads x 1 batch
  int id = blockIdx.x + 32 * (blockIdx.y + 16 * blockIdx.z);
  int swz = (id & 7) * 128 + (id >> 3);
  const int bx = swz & 31, h = (swz >> 5) & 15, b = swz >> 9;
  const int q0 = bx * 64;

  const bf16_t* qbase = Qp + ((size_t)(b * NQ + q0)) * DIM + h * HD;
  const bf16_t* kbase = Kp + ((size_t)b * NKK) * DIM + h * HD;
  const bf16_t* vbase = Vt + ((size_t)((b * HEADS + h) * HD)) * NKK;

  // ---- stage Q (64x64, reusing Ks[0]) and hoist per-wave fragments ----
  stage_swz<64>(qbase, DIM, &Ks[0][0], tid);
  __syncthreads();
  bf16x8 qf[2];
  qf[0] = lds_read8_swz(&Ks[0][0], wid * 16 + l15, lg);
  qf[1] = lds_read8_swz(&Ks[0][0], wid * 16 + l15, 4 + lg);
  __syncthreads();   // qf reads drained before K restage

  float m_ = -1e30f, l_ = 0.f;
  f32x4 o[4];
#pragma unroll
  for (int n = 0; n < 4; ++n) o[n] = (f32x4){0.f, 0.f, 0.f, 0.f};

  constexpr int NT = NKK / 64;   // 32 kv tiles

#define QK_TILE(kl, sdst)                                              \
  do {                                                                 \
    __builtin_amdgcn_s_setprio(1);                                     \
    _Pragma("unroll")                                                  \
    for (int tt = 0; tt < 4; ++tt) {                                   \
      bf16x8 kf0 = lds_read8_swz((kl), tt * 16 + l15, lg);             \
      bf16x8 kf1 = lds_read8_swz((kl), tt * 16 + l15, 4 + lg);         \
      f32x4 a = (f32x4){0.f, 0.f, 0.f, 0.f};                           \
      a = MFMA16(kf0, qf[0], a);                                       \
      a = MFMA16(kf1, qf[1], a);                                       \
      (sdst)[tt] = a;                                                  \
    }                                                                  \
    __builtin_amdgcn_s_setprio(0);                                     \
  } while (0)

  // ---- prologue: K(0),V(0) staged+drained; QK(0); K(1) staged ----
  stage_swz<64>(kbase, DIM, &Ks[0][0], tid);
  stage_swz<64>(vbase, NKK, &Vs[0][0], tid);
  asm volatile("s_waitcnt vmcnt(0)" ::: "memory");
  __builtin_amdgcn_s_barrier();
  __builtin_amdgcn_sched_barrier(0);
  f32x4 scur[4];
  QK_TILE(&Ks[0][0], scur);              // S(0)
  stage_swz<64>(kbase + (size_t)64 * DIM, DIM, &Ks[1][0], tid);   // K(1): 2 loads

  for (int t = 0; t < NT; ++t) {
    // A: entry barrier — every wave's prev-iter LDS reads are retired
    __builtin_amdgcn_s_barrier();
    __builtin_amdgcn_sched_barrier(0);

    // B: issue this iteration's stages (left in flight across barrier D)
    if (t + 1 < NT) stage_swz<64>(vbase + (t + 1) * 64, NKK, &Vs[(t + 1) & 1][0], tid);
    if (t + 2 < NT) stage_swz<64>(kbase + (size_t)(t + 2) * 64 * DIM, DIM, &Ks[t & 1][0], tid);

    // C: wait only for PREVIOUS iteration's loads (counted, never 0 mid-loop)
    if (t + 2 < NT)      asm volatile("s_waitcnt vmcnt(4)" ::: "memory");
    else if (t + 1 < NT) asm volatile("s_waitcnt vmcnt(2)" ::: "memory");
    else                 asm volatile("s_waitcnt vmcnt(0)" ::: "memory");
    // D: rendezvous — all waves' previous stages now visible in LDS
    __builtin_amdgcn_s_barrier();
    __builtin_amdgcn_sched_barrier(0);

    // E: QK(t+1) early — MFMA pipe busy while softmax(t) runs on the VALU
    f32x4 snx[4];
    if (t + 1 < NT) QK_TILE(&Ks[(t + 1) & 1][0], snx);

    // F: softmax(t): lane-local + shfl_xor(16,32); defer-max (T13)
    float rm = scur[0][0];
#pragma unroll
    for (int tt = 0; tt < 4; ++tt)
#pragma unroll
      for (int j = 0; j < 4; ++j) rm = fmaxf(rm, scur[tt][j]);
    rm = fmaxf(rm, __shfl_xor(rm, 16));
    rm = fmaxf(rm, __shfl_xor(rm, 32));
    if (!__all(rm <= m_ + 8.f)) {
      float mn = fmaxf(m_, rm);
      float al = exp2f(m_ - mn);
      m_ = mn;
      l_ *= al;
#pragma unroll
      for (int n = 0; n < 4; ++n)
#pragma unroll
        for (int j = 0; j < 4; ++j) o[n][j] *= al;
    }
    float rs = 0.f;
#pragma unroll
    for (int tt = 0; tt < 4; ++tt)
#pragma unroll
      for (int j = 0; j < 4; ++j) {
        float p = exp2f(scur[tt][j] - m_);
        scur[tt][j] = p;
        rs += p;
      }
    rs += __shfl_xor(rs, 16);
    rs += __shfl_xor(rs, 32);
    l_ += rs;

    // P^T -> per-wave LDS: row = q (l15), col = kv rotated by 8*(l15&7)
    bf16_t* Pw = &Ps[wid][0];
#pragma unroll
    for (int tt = 0; tt < 4; ++tt) {
      unsigned w0 = cvtpk_bf16(scur[tt][0], scur[tt][1]);
      unsigned w1 = cvtpk_bf16(scur[tt][2], scur[tt][3]);
      int col = (16 * tt + 4 * lg + rot) & 63;
      u32x2 pk2 = {w0, w1};
      *reinterpret_cast<u32x2*>(reinterpret_cast<char*>(Pw) + l15 * 128 + col * 2) = pk2;
    }
    asm volatile("s_waitcnt lgkmcnt(0)" ::: "memory");
    bf16x8 pf[2];
#pragma unroll
    for (int kt = 0; kt < 2; ++kt) {
      int col = (32 * kt + 8 * lg + rot) & 63;
      pf[kt] = *reinterpret_cast<const bf16x8*>(reinterpret_cast<const char*>(Pw) + l15 * 128 + col * 2);
    }

    // G: PV(t): O^T += V^T P^T from Vs[t&1]
    const bf16_t* vl = &Vs[t & 1][0];
    __builtin_amdgcn_s_setprio(1);
#pragma unroll
    for (int n = 0; n < 4; ++n) {
#pragma unroll
      for (int kt = 0; kt < 2; ++kt) {
        bf16x8 vf = lds_read8_swz(vl, n * 16 + l15, 4 * kt + lg);
        o[n] = MFMA16(vf, pf[kt], o[n]);
      }
    }
    __builtin_amdgcn_s_setprio(0);

    if (t + 1 < NT) {
#pragma unroll
      for (int tt = 0; tt < 4; ++tt) scur[tt] = snx[tt];
    }
  }
#undef QK_TILE

  // ---- epilogue: normalize, store (lane's q fixed; d = n*16 + 4lg + j) ----
  float inv = 1.f / l_;
  int q = q0 + wid * 16 + l15;
  bf16_t* ob = Xa + ((size_t)(b * NQ + q)) * DIM + h * HD;
#pragma unroll
  for (int n = 0; n < 4; ++n) {
    bf16x4 pk;
#pragma unroll
    for (int j = 0; j < 4; ++j) pk[j] = (bf16_t)(o[n][j] * inv);
    *reinterpret_cast<bf16x4*>(ob + n * 16 + 4 * lg) = pk;
  }
}

// ---------------- launcher ----------------
extern "C" void kernel_launch(void* const* d_in, const int* in_sizes, int n_in,
                              void* d_out, int out_size, void* d_ws, size_t ws_size,
                              hipStream_t stream) {
  (void)in_sizes; (void)n_in; (void)out_size; (void)ws_size;
  const float* q  = (const float*)d_in[0];
  const float* k  = (const float*)d_in[1];
  const float* v  = (const float*)d_in[2];
  const float* Wq = (const float*)d_in[5];
  const float* Wk = (const float*)d_in[6];
  const float* Wv = (const float*)d_in[7];
  const float* Wo = (const float*)d_in[8];
  const float* bo = (const float*)d_in[9];
  float* out = (float*)d_out;

  bf16_t* ws = (bf16_t*)d_ws;
  const size_t SZ_IN = (size_t)MROWS * DIM;  // 4M elems
  const size_t SZ_W  = (size_t)DIM * DIM;    // 1M elems
  bf16_t* qb  = ws;
  bf16_t* kb  = qb  + SZ_IN;
  bf16_t* vb  = kb  + SZ_IN;
  bf16_t* wqb = vb  + SZ_IN;
  bf16_t* wkb = wqb + SZ_W;
  bf16_t* wvb = wkb + SZ_W;
  bf16_t* wob = wvb + SZ_W;
  bf16_t* Qp  = wob + SZ_W;
  bf16_t* Kp  = Qp  + SZ_IN;
  bf16_t* Vtp = Kp  + SZ_IN;
  bf16_t* Xa  = qb;  // alias: qb dead after QKV projection (stream-ordered)

  cvt_all<<<dim3(1024, 16), 256, 0, stream>>>(q, k, v, Wq, Wk, Wv, Wo,
                                              qb, kb, vb, wqb, wkb, wvb, wob);

  gemm_qkv<<<dim3(24, MROWS / 128), 256, 0, stream>>>(qb, kb, vb, wqb, wkb, wvb,
                                                      Qp, Kp, Vtp);

  attn_fused<<<dim3(NQ / 64, HEADS, NB), 256, 0, stream>>>(Qp, Kp, Vtp, Xa);

  gemm_out<<<dim3(DIM / 128, MROWS / 128), 256, 0, stream>>>(Xa, wob, out, bo);
}

// Round 11
// 157.843 us; speedup vs baseline: 1.0493x; 1.0493x over previous
//
#include <hip/hip_runtime.h>
#include <hip/hip_bf16.h>
#include <stdint.h>

typedef __bf16 bf16_t;
typedef __bf16 bf16x4 __attribute__((ext_vector_type(4)));
typedef __bf16 bf16x8 __attribute__((ext_vector_type(8)));
typedef float  f32x4  __attribute__((ext_vector_type(4)));
typedef unsigned u32x2 __attribute__((ext_vector_type(2)));

#define MFMA16(a,b,c) __builtin_amdgcn_mfma_f32_16x16x32_bf16((a),(b),(c),0,0,0)

static constexpr int DIM = 1024, HEADS = 16, HD = 64, NB = 2, NQ = 2048, NKK = 2048;
static constexpr int MROWS = NB * NQ; // 4096 token rows
static constexpr float SCALE_Q = 0.18033688011112042f; // 0.125 * log2(e)

// ---------------- fused f32 -> bf16 convert (all 7 tensors, 1 launch) -------
__global__ void cvt_all(const float* __restrict__ q, const float* __restrict__ k,
                        const float* __restrict__ v, const float* __restrict__ wq,
                        const float* __restrict__ wk, const float* __restrict__ wv,
                        const float* __restrict__ wo,
                        bf16_t* qb, bf16_t* kb, bf16_t* vb,
                        bf16_t* wqb, bf16_t* wkb, bf16_t* wvb, bf16_t* wob) {
  const int seg = blockIdx.y;
  const float* src; bf16_t* dst;
  size_t base;
  if (seg < 12) {
    int t = seg >> 2;                       // 0=q 1=k 2=v
    src = t == 0 ? q : t == 1 ? k : v;
    dst = t == 0 ? qb : t == 1 ? kb : vb;
    base = (size_t)(seg & 3) * 262144;      // quarter of 1M float4
  } else {
    int t = seg - 12;
    src = t == 0 ? wq : t == 1 ? wk : t == 2 ? wv : wo;
    dst = t == 0 ? wqb : t == 1 ? wkb : t == 2 ? wvb : wob;
    base = 0;
  }
  size_t i = base + blockIdx.x * 256 + threadIdx.x;
  float4 val = reinterpret_cast<const float4*>(src)[i];
  bf16x4 o;
  o[0] = (bf16_t)val.x; o[1] = (bf16_t)val.y; o[2] = (bf16_t)val.z; o[3] = (bf16_t)val.w;
  *reinterpret_cast<bf16x4*>(dst + i * 4) = o;
}

// ---------------- LDS staging with chunk-XOR swizzle ----------------
template<int ROWS, int TPB = 256>
__device__ __forceinline__ void stage_swz(const bf16_t* gbase, int gstride, bf16_t* lds, int tid) {
#pragma unroll
  for (int c = 0; c < ROWS * 8 / TPB; ++c) {
    int p = c * TPB + tid;                        // 16B-chunk index
    int r = p >> 3, x = p & 7;
    const bf16_t* src = gbase + (size_t)r * gstride + ((x ^ (r & 7)) << 3);
    __builtin_amdgcn_global_load_lds(
        (const __attribute__((address_space(1))) void*)src,
        (__attribute__((address_space(3))) void*)(lds + (p << 3)),
        16, 0, 0);
  }
}

__device__ __forceinline__ bf16x8 lds_read8_swz(const bf16_t* lds, int row, int chunk) {
  int sc = chunk ^ (row & 7);
  return *reinterpret_cast<const bf16x8*>(lds + row * 64 + (sc << 3));
}

__device__ __forceinline__ unsigned cvtpk_bf16(float lo, float hi) {
  unsigned r;
  asm("v_cvt_pk_bf16_f32 %0, %1, %2" : "=v"(r) : "v"(lo), "v"(hi));
  return r;
}

// ---------------- fused QKV projection GEMM --------------------------------
// CROSS-attention: each projection has its OWN token input.
__global__ __launch_bounds__(256) void gemm_qkv(const bf16_t* __restrict__ qb,
                                                const bf16_t* __restrict__ kb,
                                                const bf16_t* __restrict__ vb,
                                                const bf16_t* __restrict__ Wq,
                                                const bf16_t* __restrict__ Wk,
                                                const bf16_t* __restrict__ Wv,
                                                bf16_t* __restrict__ Qp,
                                                bf16_t* __restrict__ Kp,
                                                bf16_t* __restrict__ Vt) {
  constexpr int K = DIM, N = DIM;
  __shared__ __align__(16) bf16_t As[128 * 64];
  __shared__ __align__(16) bf16_t Bs[128 * 64];
  const int tid = threadIdx.x;
  const int lane = tid & 63, wid = tid >> 6;
  const int l15 = lane & 15, lg = lane >> 4;
  const int wr = wid >> 1, wc = wid & 1;
  const int bn = blockIdx.x, bm = blockIdx.y;
  const int sel = bn >> 3, bnl = bn & 7;

  const bf16_t* A  = sel == 0 ? qb : sel == 1 ? kb : vb;
  const bf16_t* Bt = sel == 0 ? Wq : sel == 1 ? Wk : Wv;
  const bf16_t* Abase = A + (size_t)(bm * 128) * K;
  const bf16_t* Bbase = Bt + (size_t)(bnl * 128) * K;

  f32x4 acc[4][4];
#pragma unroll
  for (int m = 0; m < 4; ++m)
#pragma unroll
    for (int n = 0; n < 4; ++n) acc[m][n] = (f32x4){0.f, 0.f, 0.f, 0.f};

  for (int k0 = 0; k0 < K; k0 += 64) {
    __syncthreads();
    stage_swz<128>(Abase + k0, K, As, tid);
    stage_swz<128>(Bbase + k0, K, Bs, tid);
    __syncthreads();
#pragma unroll
    for (int kk = 0; kk < 2; ++kk) {
      bf16x8 af[4], bfr[4];
#pragma unroll
      for (int m = 0; m < 4; ++m) af[m] = lds_read8_swz(As, wr * 64 + m * 16 + l15, kk * 4 + lg);
#pragma unroll
      for (int n = 0; n < 4; ++n) bfr[n] = lds_read8_swz(Bs, wc * 64 + n * 16 + l15, kk * 4 + lg);
#pragma unroll
      for (int m = 0; m < 4; ++m)
#pragma unroll
        for (int n = 0; n < 4; ++n)
          acc[m][n] = MFMA16(af[m], bfr[n], acc[m][n]);
    }
  }

  if (sel == 2) {
#pragma unroll
    for (int m = 0; m < 4; ++m) {
      int row0 = bm * 128 + wr * 64 + m * 16 + lg * 4;
      int bb = row0 >> 11, kv = row0 & 2047;
#pragma unroll
      for (int n = 0; n < 4; ++n) {
        int col = bnl * 128 + wc * 64 + n * 16 + l15;
        int hh = col >> 6, dd = col & 63;
        bf16x4 pk;
#pragma unroll
        for (int j = 0; j < 4; ++j) pk[j] = (bf16_t)acc[m][n][j];
        *reinterpret_cast<bf16x4*>(Vt + (((size_t)((bb * 16 + hh) * 64 + dd)) << 11) + kv) = pk;
      }
    }
  } else {
    bf16_t* Cout = sel == 0 ? Qp : Kp;
    const float scale = sel == 0 ? SCALE_Q : 1.0f;
#pragma unroll
    for (int m = 0; m < 4; ++m)
#pragma unroll
      for (int n = 0; n < 4; ++n)
#pragma unroll
        for (int j = 0; j < 4; ++j) {
          int row = bm * 128 + wr * 64 + m * 16 + lg * 4 + j;
          int col = bnl * 128 + wc * 64 + n * 16 + l15;
          Cout[(size_t)row * N + col] = (bf16_t)(acc[m][n][j] * scale);
        }
  }
}

// ---------------- output projection GEMM (f32 + bias) ----------------------
__global__ __launch_bounds__(256) void gemm_out(const bf16_t* __restrict__ A,
                                                const bf16_t* __restrict__ Bt,
                                                float* __restrict__ Cout,
                                                const float* __restrict__ bias) {
  constexpr int K = DIM, N = DIM;
  __shared__ __align__(16) bf16_t As[128 * 64];
  __shared__ __align__(16) bf16_t Bs[128 * 64];
  const int tid = threadIdx.x;
  const int lane = tid & 63, wid = tid >> 6;
  const int l15 = lane & 15, lg = lane >> 4;
  const int wr = wid >> 1, wc = wid & 1;
  const int bn = blockIdx.x, bm = blockIdx.y;

  const bf16_t* Abase = A + (size_t)(bm * 128) * K;
  const bf16_t* Bbase = Bt + (size_t)(bn * 128) * K;

  f32x4 acc[4][4];
#pragma unroll
  for (int m = 0; m < 4; ++m)
#pragma unroll
    for (int n = 0; n < 4; ++n) acc[m][n] = (f32x4){0.f, 0.f, 0.f, 0.f};

  for (int k0 = 0; k0 < K; k0 += 64) {
    __syncthreads();
    stage_swz<128>(Abase + k0, K, As, tid);
    stage_swz<128>(Bbase + k0, K, Bs, tid);
    __syncthreads();
#pragma unroll
    for (int kk = 0; kk < 2; ++kk) {
      bf16x8 af[4], bfr[4];
#pragma unroll
      for (int m = 0; m < 4; ++m) af[m] = lds_read8_swz(As, wr * 64 + m * 16 + l15, kk * 4 + lg);
#pragma unroll
      for (int n = 0; n < 4; ++n) bfr[n] = lds_read8_swz(Bs, wc * 64 + n * 16 + l15, kk * 4 + lg);
#pragma unroll
      for (int m = 0; m < 4; ++m)
#pragma unroll
        for (int n = 0; n < 4; ++n)
          acc[m][n] = MFMA16(af[m], bfr[n], acc[m][n]);
    }
  }

#pragma unroll
  for (int m = 0; m < 4; ++m)
#pragma unroll
    for (int n = 0; n < 4; ++n)
#pragma unroll
      for (int j = 0; j < 4; ++j) {
        int row = bm * 128 + wr * 64 + m * 16 + lg * 4 + j;
        int col = bn * 128 + wc * 64 + n * 16 + l15;
        Cout[(size_t)row * N + col] = acc[m][n][j] + bias[col];
      }
}

// ---------------- fused flash attention (8 waves, QBLK=128, 50% occupancy) --
// grid (NQ/128, HEADS, B) XCD-swizzled; 8 waves x 16 q (q = wid*16 + l15).
// Per-wave code identical to R10 (proven). K/V staged once per block, shared
// by 8 waves. LDS = 48KB -> 2 blocks/CU x 8 waves = 16 waves/CU (~50% occ).
// Steady-state iter t (counted vmcnt, never 0 mid-loop; 1 load/wave/stage):
//   A: s_barrier  B: stage V(t+1),K(t+2)  C: vmcnt(2)=prev iter's loads
//   D: s_barrier  E: QK(t+1)  F: softmax(t)+P  G: PV(t)
// Tail peels vmcnt 2 -> 1 -> 0.
__global__ __launch_bounds__(512) void attn_fused(const bf16_t* __restrict__ Qp,
                                                  const bf16_t* __restrict__ Kp,
                                                  const bf16_t* __restrict__ Vt,
                                                  bf16_t* __restrict__ Xa) {
  __shared__ __align__(16) bf16_t Ks[2][64 * 64];
  __shared__ __align__(16) bf16_t Vs[2][64 * 64];
  __shared__ __align__(16) bf16_t Ps[8][16 * 64];   // per-wave, pad-free, row-rotated
  const int tid = threadIdx.x;
  const int lane = tid & 63, wid = tid >> 6;        // wid 0..7
  const int l15 = lane & 15, lg = lane >> 4;
  const int rot = (l15 & 7) * 8;

  // bijective XCD swizzle over 512 workgroups: XCD k hosts heads 4k..4k+3
  int id = blockIdx.x + 16 * (blockIdx.y + 16 * blockIdx.z);
  int swz = (id & 7) * 64 + (id >> 3);
  const int bx = swz & 15, h = (swz >> 4) & 15, b = swz >> 8;
  const int q0 = bx * 128;

  const bf16_t* qbase = Qp + ((size_t)(b * NQ + q0)) * DIM + h * HD;
  const bf16_t* kbase = Kp + ((size_t)b * NKK) * DIM + h * HD;
  const bf16_t* vbase = Vt + ((size_t)((b * HEADS + h) * HD)) * NKK;

  // ---- stage Q (128x64 = 16KB across Ks[0..1]) and hoist per-wave frags ----
  stage_swz<128, 512>(qbase, DIM, &Ks[0][0], tid);
  __syncthreads();
  bf16x8 qf[2];
  qf[0] = lds_read8_swz(&Ks[0][0], wid * 16 + l15, lg);
  qf[1] = lds_read8_swz(&Ks[0][0], wid * 16 + l15, 4 + lg);
  __syncthreads();   // qf reads drained before K restage

  float m_ = -1e30f, l_ = 0.f;
  f32x4 o[4];
#pragma unroll
  for (int n = 0; n < 4; ++n) o[n] = (f32x4){0.f, 0.f, 0.f, 0.f};

  constexpr int NT = NKK / 64;   // 32 kv tiles

#define QK_TILE(kl, sdst)                                              \
  do {                                                                 \
    __builtin_amdgcn_s_setprio(1);                                     \
    _Pragma("unroll")                                                  \
    for (int tt = 0; tt < 4; ++tt) {                                   \
      bf16x8 kf0 = lds_read8_swz((kl), tt * 16 + l15, lg);             \
      bf16x8 kf1 = lds_read8_swz((kl), tt * 16 + l15, 4 + lg);         \
      f32x4 a = (f32x4){0.f, 0.f, 0.f, 0.f};                           \
      a = MFMA16(kf0, qf[0], a);                                       \
      a = MFMA16(kf1, qf[1], a);                                       \
      (sdst)[tt] = a;                                                  \
    }                                                                  \
    __builtin_amdgcn_s_setprio(0);                                     \
  } while (0)

  // ---- prologue: K(0),V(0) staged+drained; QK(0); K(1) staged ----
  stage_swz<64, 512>(kbase, DIM, &Ks[0][0], tid);
  stage_swz<64, 512>(vbase, NKK, &Vs[0][0], tid);
  asm volatile("s_waitcnt vmcnt(0)" ::: "memory");
  __builtin_amdgcn_s_barrier();
  __builtin_amdgcn_sched_barrier(0);
  f32x4 scur[4];
  QK_TILE(&Ks[0][0], scur);              // S(0)
  stage_swz<64, 512>(kbase + (size_t)64 * DIM, DIM, &Ks[1][0], tid);   // K(1): 1 load

  for (int t = 0; t < NT; ++t) {
    // A: entry barrier — every wave's prev-iter LDS reads are retired
    __builtin_amdgcn_s_barrier();
    __builtin_amdgcn_sched_barrier(0);

    // B: issue this iteration's stages (left in flight across barrier D)
    if (t + 1 < NT) stage_swz<64, 512>(vbase + (t + 1) * 64, NKK, &Vs[(t + 1) & 1][0], tid);
    if (t + 2 < NT) stage_swz<64, 512>(kbase + (size_t)(t + 2) * 64 * DIM, DIM, &Ks[t & 1][0], tid);

    // C: wait only for PREVIOUS iteration's loads (counted, never 0 mid-loop)
    if (t + 2 < NT)      asm volatile("s_waitcnt vmcnt(2)" ::: "memory");
    else if (t + 1 < NT) asm volatile("s_waitcnt vmcnt(1)" ::: "memory");
    else                 asm volatile("s_waitcnt vmcnt(0)" ::: "memory");
    // D: rendezvous — all waves' previous stages now visible in LDS
    __builtin_amdgcn_s_barrier();
    __builtin_amdgcn_sched_barrier(0);

    // E: QK(t+1) early — MFMA pipe busy while softmax(t) runs on the VALU
    f32x4 snx[4];
    if (t + 1 < NT) QK_TILE(&Ks[(t + 1) & 1][0], snx);

    // F: softmax(t): lane-local + shfl_xor(16,32); defer-max (T13)
    float rm = scur[0][0];
#pragma unroll
    for (int tt = 0; tt < 4; ++tt)
#pragma unroll
      for (int j = 0; j < 4; ++j) rm = fmaxf(rm, scur[tt][j]);
    rm = fmaxf(rm, __shfl_xor(rm, 16));
    rm = fmaxf(rm, __shfl_xor(rm, 32));
    if (!__all(rm <= m_ + 8.f)) {
      float mn = fmaxf(m_, rm);
      float al = exp2f(m_ - mn);
      m_ = mn;
      l_ *= al;
#pragma unroll
      for (int n = 0; n < 4; ++n)
#pragma unroll
        for (int j = 0; j < 4; ++j) o[n][j] *= al;
    }
    float rs = 0.f;
#pragma unroll
    for (int tt = 0; tt < 4; ++tt)
#pragma unroll
      for (int j = 0; j < 4; ++j) {
        float p = exp2f(scur[tt][j] - m_);
        scur[tt][j] = p;
        rs += p;
      }
    rs += __shfl_xor(rs, 16);
    rs += __shfl_xor(rs, 32);
    l_ += rs;

    // P^T -> per-wave LDS: row = q (l15), col = kv rotated by 8*(l15&7)
    bf16_t* Pw = &Ps[wid][0];
#pragma unroll
    for (int tt = 0; tt < 4; ++tt) {
      unsigned w0 = cvtpk_bf16(scur[tt][0], scur[tt][1]);
      unsigned w1 = cvtpk_bf16(scur[tt][2], scur[tt][3]);
      int col = (16 * tt + 4 * lg + rot) & 63;
      u32x2 pk2 = {w0, w1};
      *reinterpret_cast<u32x2*>(reinterpret_cast<char*>(Pw) + l15 * 128 + col * 2) = pk2;
    }
    asm volatile("s_waitcnt lgkmcnt(0)" ::: "memory");
    bf16x8 pf[2];
#pragma unroll
    for (int kt = 0; kt < 2; ++kt) {
      int col = (32 * kt + 8 * lg + rot) & 63;
      pf[kt] = *reinterpret_cast<const bf16x8*>(reinterpret_cast<const char*>(Pw) + l15 * 128 + col * 2);
    }

    // G: PV(t): O^T += V^T P^T from Vs[t&1]
    const bf16_t* vl = &Vs[t & 1][0];
    __builtin_amdgcn_s_setprio(1);
#pragma unroll
    for (int n = 0; n < 4; ++n) {
#pragma unroll
      for (int kt = 0; kt < 2; ++kt) {
        bf16x8 vf = lds_read8_swz(vl, n * 16 + l15, 4 * kt + lg);
        o[n] = MFMA16(vf, pf[kt], o[n]);
      }
    }
    __builtin_amdgcn_s_setprio(0);

    if (t + 1 < NT) {
#pragma unroll
      for (int tt = 0; tt < 4; ++tt) scur[tt] = snx[tt];
    }
  }
#undef QK_TILE

  // ---- epilogue: normalize, store (lane's q fixed; d = n*16 + 4lg + j) ----
  float inv = 1.f / l_;
  int q = q0 + wid * 16 + l15;
  bf16_t* ob = Xa + ((size_t)(b * NQ + q)) * DIM + h * HD;
#pragma unroll
  for (int n = 0; n < 4; ++n) {
    bf16x4 pk;
#pragma unroll
    for (int j = 0; j < 4; ++j) pk[j] = (bf16_t)(o[n][j] * inv);
    *reinterpret_cast<bf16x4*>(ob + n * 16 + 4 * lg) = pk;
  }
}

// ---------------- launcher ----------------
extern "C" void kernel_launch(void* const* d_in, const int* in_sizes, int n_in,
                              void* d_out, int out_size, void* d_ws, size_t ws_size,
                              hipStream_t stream) {
  (void)in_sizes; (void)n_in; (void)out_size; (void)ws_size;
  const float* q  = (const float*)d_in[0];
  const float* k  = (const float*)d_in[1];
  const float* v  = (const float*)d_in[2];
  const float* Wq = (const float*)d_in[5];
  const float* Wk = (const float*)d_in[6];
  const float* Wv = (const float*)d_in[7];
  const float* Wo = (const float*)d_in[8];
  const float* bo = (const float*)d_in[9];
  float* out = (float*)d_out;

  bf16_t* ws = (bf16_t*)d_ws;
  const size_t SZ_IN = (size_t)MROWS * DIM;  // 4M elems
  const size_t SZ_W  = (size_t)DIM * DIM;    // 1M elems
  bf16_t* qb  = ws;
  bf16_t* kb  = qb  + SZ_IN;
  bf16_t* vb  = kb  + SZ_IN;
  bf16_t* wqb = vb  + SZ_IN;
  bf16_t* wkb = wqb + SZ_W;
  bf16_t* wvb = wkb + SZ_W;
  bf16_t* wob = wvb + SZ_W;
  bf16_t* Qp  = wob + SZ_W;
  bf16_t* Kp  = Qp  + SZ_IN;
  bf16_t* Vtp = Kp  + SZ_IN;
  bf16_t* Xa  = qb;  // alias: qb dead after QKV projection (stream-ordered)

  cvt_all<<<dim3(1024, 16), 256, 0, stream>>>(q, k, v, Wq, Wk, Wv, Wo,
                                              qb, kb, vb, wqb, wkb, wvb, wob);

  gemm_qkv<<<dim3(24, MROWS / 128), 256, 0, stream>>>(qb, kb, vb, wqb, wkb, wvb,
                                                      Qp, Kp, Vtp);

  attn_fused<<<dim3(NQ / 128, HEADS, NB), 512, 0, stream>>>(Qp, Kp, Vtp, Xa);

  gemm_out<<<dim3(DIM / 128, MROWS / 128), 256, 0, stream>>>(Xa, wob, out, bo);
}